// Round 27
// baseline (31.931 us; speedup 1.0000x reference)
//
#include <hip/hip_runtime.h>
#include <stdint.h>

#define BB 2
#define DD 64
#define HH 128
#define WW 128
#define NVOX (DD*HH*WW)        // 2^20 per batch
#define TOTAL (BB*NVOX)        // 2097152
#define NWORDS (TOTAL/16)      // 131072 uint16 mask words per volume
#define EGRID (BB*DD*2)        // 256 blocks
#define BCNTN (EGRID*4)        // per-block private counter slots
#define CAP (1<<20)            // residual list capacity
#define MAXD2 36227            // 63^2+127^2+127^2
#define INF_I 0x7FFFFFFF

__device__ __forceinline__ int aload(const int* p)
{
    return __hip_atomic_load(p, __ATOMIC_RELAXED, __HIP_MEMORY_SCOPE_AGENT);
}

__device__ __forceinline__ void astore(int* p, int v)
{
    __hip_atomic_store(p, v, __ATOMIC_RELAXED, __HIP_MEMORY_SCOPE_AGENT);
}

// 4-bit spread: bit l -> bit 4l
__device__ __forceinline__ uint32_t spread4(uint32_t n)
{
    return (n & 1u) | ((n & 2u) << 3) | ((n & 4u) << 6) | ((n & 8u) << 9);
}

// ---------- bitpack: coalesced float4 load + wave-ballot pack --------------
__global__ __launch_bounds__(256)
void bitpack_kernel(const float* __restrict__ pred, const float* __restrict__ targ,
                    uint16_t* __restrict__ pb, uint16_t* __restrict__ tb,
                    int* __restrict__ listCnt)
{
    int gt = blockIdx.x * 256 + threadIdx.x;       // 0..TOTAL/4-1
    if (gt == 0) listCnt[0] = 0;
    int lane = threadIdx.x & 63;
    int wbase = (gt & ~63) >> 2;                   // wave's first u16 word index

    const float4* srcs[2] = {(const float4*)pred, (const float4*)targ};
    uint16_t* dsts[2] = {pb, tb};
    #pragma unroll
    for (int s = 0; s < 2; ++s) {
        float4 f = srcs[s][gt];
        uint64_t B0 = __ballot(f.x > 0.5f);
        uint64_t B1 = __ballot(f.y > 0.5f);
        uint64_t B2 = __ballot(f.z > 0.5f);
        uint64_t B3 = __ballot(f.w > 0.5f);
        if (lane < 16) {
            uint32_t n0 = (uint32_t)(B0 >> (4 * lane)) & 0xFu;
            uint32_t n1 = (uint32_t)(B1 >> (4 * lane)) & 0xFu;
            uint32_t n2 = (uint32_t)(B2 >> (4 * lane)) & 0xFu;
            uint32_t n3 = (uint32_t)(B3 >> (4 * lane)) & 0xFu;
            uint32_t word = spread4(n0) | (spread4(n1) << 1)
                          | (spread4(n2) << 2) | (spread4(n3) << 3);
            dsts[s][wbase + lane] = (uint16_t)word;
        }
    }
}

// ---------- bit-volume helpers (percentile kernel only) --------------------
__device__ __forceinline__ int getbit(const uint16_t* __restrict__ M,
                                      int b, int z, int y, int x)
{
    return (M[(((size_t)(b * DD + z)) << 10) + (y << 3) + (x >> 4)] >> (x & 15)) & 1;
}

__device__ __forceinline__ bool is_edge(const uint16_t* __restrict__ M,
                                        int b, int z, int y, int x)
{
    if (!getbit(M, b, z, y, x)) return false;
    if (x == 0 || x == WW-1 || y == 0 || y == HH-1 || z == 0 || z == DD-1) return true;
    int er = getbit(M,b,z,y,x-1) & getbit(M,b,z,y,x+1) &
             getbit(M,b,z,y-1,x) & getbit(M,b,z,y+1,x) &
             getbit(M,b,z-1,y,x) & getbit(M,b,z+1,y,x);
    return !er;
}

// ---------- LEAN edge + word-parallel r<=1 distance + private stores -------
__global__ __launch_bounds__(1024)
void edge_dist_hist(const uint16_t* __restrict__ pb, const uint16_t* __restrict__ tb,
                    int* __restrict__ bcnt, int* __restrict__ listCnt,
                    int* __restrict__ list)
{
    __shared__ uint16_t ownm[3][1024];   // own mask slices  z-1..z+1
    __shared__ uint16_t othm[5][1024];   // other mask slices z-2..z+2
    __shared__ uint16_t tedge[3][1024];  // other EDGE slices z-1..z+1
    __shared__ int lh[4];
    int gid = blockIdx.x, tid = threadIdx.x;
    int dir = gid & 1;
    int bz  = gid >> 1;
    int b   = bz >> 6, z = bz & (DD - 1);
    const uint16_t* own = dir ? tb : pb;   // dir0: E = pred edges
    const uint16_t* oth = dir ? pb : tb;   // dir0: distances to targ edges

    {   // cooperative load: 8 slices x 1024 words (zero out-of-range slices)
        int s = tid >> 7, off = (tid & 127) * 8;
        int zs = (s < 3) ? z + s - 1 : z + s - 5;
        const uint16_t* src = (s < 3) ? own : oth;
        uint16_t* dst = (s < 3) ? &ownm[s][off] : &othm[s - 3][off];
        if (zs >= 0 && zs < DD)
            *(uint4*)dst = *(const uint4*)(src + (((size_t)(b * DD + zs)) << 10) + off);
        else
            *(uint4*)dst = make_uint4(0, 0, 0, 0);
    }
    if (tid < 4) lh[tid] = 0;
    __syncthreads();

    int w = tid, y = w >> 3, wx = w & 7;

    // phase A: other-surface edge words for dz in {-1,0,1}
    #pragma unroll
    for (int dzi = 0; dzi < 3; ++dzi) {
        uint32_t c = othm[dzi + 1][w];
        uint32_t l = wx > 0 ? othm[dzi + 1][w - 1] : 0;
        uint32_t r = wx < 7 ? othm[dzi + 1][w + 1] : 0;
        uint32_t ext = (l >> 15) | (c << 1) | ((r & 1u) << 17);
        uint32_t m = (ext >> 1) & 0xFFFFu, L = ext & 0xFFFFu, R = (ext >> 2) & 0xFFFFu;
        uint32_t ym = y > 0   ? othm[dzi + 1][w - 8] : 0;
        uint32_t yp = y < 127 ? othm[dzi + 1][w + 8] : 0;
        uint32_t zm = othm[dzi][w], zp = othm[dzi + 2][w];
        uint32_t er = m & L & R & ym & yp & zm & zp;
        tedge[dzi][w] = (uint16_t)(m & ~er);
    }

    // E: own-surface edge word
    uint32_t E;
    {
        uint32_t c = ownm[1][w];
        uint32_t l = wx > 0 ? ownm[1][w - 1] : 0;
        uint32_t r = wx < 7 ? ownm[1][w + 1] : 0;
        uint32_t ext = (l >> 15) | (c << 1) | ((r & 1u) << 17);
        uint32_t m = (ext >> 1) & 0xFFFFu, L = ext & 0xFFFFu, R = (ext >> 2) & 0xFFFFu;
        uint32_t ym = y > 0   ? ownm[1][w - 8] : 0;
        uint32_t yp = y < 127 ? ownm[1][w + 8] : 0;
        uint32_t zm = ownm[0][w], zp = ownm[2][w];
        E = m & ~(m & L & R & ym & yp & zm & zp);
    }
    __syncthreads();   // tedge ready

    // phase B: M0..M3 (has oth-edge at d^2=0/1/2/3) from tedge ext rows
    uint32_t M0 = 0, M1 = 0, M2 = 0, M3 = 0;
    #pragma unroll
    for (int dzi = 0; dzi < 3; ++dzi) {
        #pragma unroll
        for (int dyy = -1; dyy <= 1; ++dyy) {
            int yy = y + dyy;
            uint32_t c = 0, l = 0, r = 0;
            if (yy >= 0 && yy < HH) {
                int w2 = (yy << 3) + wx;
                c = tedge[dzi][w2];
                l = wx > 0 ? tedge[dzi][w2 - 1] : 0;
                r = wx < 7 ? tedge[dzi][w2 + 1] : 0;
            }
            uint32_t ext = (l >> 15) | (c << 1) | ((r & 1u) << 17);
            uint32_t s0 = (ext >> 1) & 0xFFFFu;                      // dx = 0
            uint32_t s1 = (ext & 0xFFFFu) | ((ext >> 2) & 0xFFFFu);  // dx = +-1
            int a = (dzi == 1 ? 0 : 1) + (dyy == 0 ? 0 : 1);
            if (a == 0)      { M0 |= s0; M1 |= s1; }
            else if (a == 1) { M1 |= s0; M2 |= s1; }
            else             { M2 |= s0; M3 |= s1; }
        }
    }

    uint32_t rem = E;
    int c0 = __popc(rem & M0); rem &= ~M0;
    int c1 = __popc(rem & M1); rem &= ~M1;
    int c2 = __popc(rem & M2); rem &= ~M2;
    int c3 = __popc(rem & M3); rem &= ~M3;

    int g = b * 2 + dir;

    // residual voxels (boundary-clipped cubes, ~2-4 total): append POSITION
    while (rem) {
        int i = __builtin_ctz(rem); rem &= rem - 1;
        int x = wx * 16 + i;
        int pos = atomicAdd(listCnt, 1);
        if (pos < CAP)
            astore(&list[pos], g | (z << 2) | (y << 8) | (x << 15));
    }

    // wave reduce the 4 hot counters, one LDS atomic per wave, private store
    int lane = tid & 63;
    #pragma unroll
    for (int o = 1; o < 64; o <<= 1) {
        c0 += __shfl_xor(c0, o, 64);
        c1 += __shfl_xor(c1, o, 64);
        c2 += __shfl_xor(c2, o, 64);
        c3 += __shfl_xor(c3, o, 64);
    }
    if (lane == 0) {
        if (c0) atomicAdd(&lh[0], c0);
        if (c1) atomicAdd(&lh[1], c1);
        if (c2) atomicAdd(&lh[2], c2);
        if (c3) atomicAdd(&lh[3], c3);
    }
    __syncthreads();
    if (tid < 4)
        astore(&bcnt[gid * 4 + tid], lh[tid]);
}

// ---------- percentile tail: 1 block, wave w handles g=w -------------------
__global__ __launch_bounds__(256)
void percentile_kernel(const uint16_t* __restrict__ pb, const uint16_t* __restrict__ tb,
                       const int* __restrict__ bcnt, const int* __restrict__ listCnt,
                       int* __restrict__ list, float* __restrict__ out)
{
    int tid = threadIdx.x, lane = tid & 63, wv = tid >> 6;
    int nL = aload(listCnt); if (nL > CAP) nL = CAP;

    // resolve each residual with a WAVE-PARALLEL expanding-shell scan
    for (int idx = wv; idx < nL; idx += 4) {
        int e = aload(&list[idx]);
        int g2 = e & 3, zz0 = (e >> 2) & 63, yy0 = (e >> 8) & 127, xx0 = (e >> 15) & 127;
        const uint16_t* M = (g2 & 1) ? pb : tb;   // oth volume for this g
        int bb = g2 >> 1;
        int best = INF_I;
        for (int r = 2; r <= 127; ++r) {
            if (best <= r * r) break;
            int side = 2 * r + 1, npts = side * side * side;
            int lmin = INF_I;
            for (int k = lane; k < npts; k += 64) {
                int dzz = k / (side * side) - r;
                int r2  = k % (side * side);
                int dyy = r2 / side - r;
                int dxx = r2 % side - r;
                int cheb = max(abs(dzz), max(abs(dyy), abs(dxx)));
                if (cheb != r) continue;
                int zz = zz0 + dzz, yy = yy0 + dyy, xx = xx0 + dxx;
                if (zz < 0 || zz >= DD || yy < 0 || yy >= HH || xx < 0 || xx >= WW) continue;
                if (is_edge(M, bb, zz, yy, xx))
                    lmin = min(lmin, dzz*dzz + dyy*dyy + dxx*dxx);
            }
            #pragma unroll
            for (int o = 1; o < 64; o <<= 1) lmin = min(lmin, __shfl_xor(lmin, o, 64));
            best = min(best, lmin);
        }
        if (best > MAXD2) best = MAXD2;
        if (lane == 0)
            astore(&list[idx], (g2 << 16) | best);
    }
    __syncthreads();

    {
        int gg = wv;
        int bsel = gg >> 1, dsel = gg & 1;

        // sum this g's 64 per-block slots (one slot per lane)
        int gid2 = ((bsel * 64) + lane) * 2 + dsel;
        int h0 = aload(&bcnt[gid2 * 4 + 0]);
        int h1 = aload(&bcnt[gid2 * 4 + 1]);
        int h2 = aload(&bcnt[gid2 * 4 + 2]);
        int h3 = aload(&bcnt[gid2 * 4 + 3]);
        #pragma unroll
        for (int o = 1; o < 64; o <<= 1) {
            h0 += __shfl_xor(h0, o, 64);
            h1 += __shfl_xor(h1, o, 64);
            h2 += __shfl_xor(h2, o, 64);
            h3 += __shfl_xor(h3, o, 64);
        }

        // count of this g's list entries (wave-uniform after reduce)
        int cg = 0;
        for (int i = lane; i < nL; i += 64) {
            int e = aload(&list[i]);
            if ((e >> 16) == gg) cg++;
        }
        #pragma unroll
        for (int o = 1; o < 64; o <<= 1) cg += __shfl_xor(cg, o, 64);

        int n = h0 + h1 + h2 + h3 + cg;
        int hotTot = n - cg;

        float pos = 0.95f * (float)(n - 1);
        float fpos = floorf(pos);
        int lo = (int)fpos;
        int nm1 = n - 1; if (nm1 < 0) nm1 = 0;
        if (lo < 0) lo = 0;
        if (lo > nm1) lo = nm1;
        int hi = lo + 1; if (hi > nm1) hi = nm1;
        float frac = pos - fpos;

        int sel[2]; int ranks[2] = {lo, hi};
        #pragma unroll
        for (int ri = 0; ri < 2; ++ri) {
            int r = ranks[ri];
            int v;
            if      (r < h0)               v = 0;
            else if (r < h0 + h1)          v = 1;
            else if (r < h0 + h1 + h2)     v = 2;
            else if (r < hotTot)           v = 3;
            else {
                int k = r - hotTot;        // 0 <= k < cg
                int loV = 4, hiV = MAXD2;
                while (loV < hiV) {
                    int mid = (loV + hiV) >> 1;
                    int c = 0;
                    for (int i = lane; i < nL; i += 64) {
                        int e = aload(&list[i]);
                        if ((e >> 16) == gg && (e & 0xFFFF) <= mid) c++;
                    }
                    #pragma unroll
                    for (int o = 1; o < 64; o <<= 1) c += __shfl_xor(c, o, 64);
                    if (c >= k + 1) hiV = mid; else loV = mid + 1;
                }
                v = loV;
            }
            sel[ri] = v;
        }
        if (lane == 0) {
            float a = sqrtf((float)sel[0]);
            float bv = sqrtf((float)sel[1]);
            float val = a + frac * (bv - a);
            atomicMax((int*)out + (gg >> 1), __float_as_int(val));  // val>=0
        }
    }
}

extern "C" void kernel_launch(void* const* d_in, const int* in_sizes, int n_in,
                              void* d_out, int out_size, void* d_ws, size_t ws_size,
                              hipStream_t stream)
{
    const float* pred = (const float*)d_in[0];
    const float* targ = (const float*)d_in[1];
    float* out = (float*)d_out;

    uint8_t* ws = (uint8_t*)d_ws;
    uint16_t* pb = (uint16_t*)ws;                    // NWORDS u16 (16B-aligned)
    uint16_t* tb = pb + NWORDS;                      // NWORDS u16
    int* bcnt    = (int*)(tb + NWORDS);              // BCNTN ints (private slots)
    int* listCnt = bcnt + BCNTN;                     // 1 int (zeroed by bitpack)
    int* list    = listCnt + 1;                      // CAP ints (residuals)

    // PROBE: run the full pipeline TWICE (idempotent). Second run is
    // cache-warm; marginal cost = warm-pipeline cost. Remove next round.
    bitpack_kernel<<<(TOTAL/4)/256, 256, 0, stream>>>(pred, targ, pb, tb, listCnt);
    edge_dist_hist<<<EGRID, 1024, 0, stream>>>(pb, tb, bcnt, listCnt, list);
    percentile_kernel<<<1, 256, 0, stream>>>(pb, tb, bcnt, listCnt, list, out);
    bitpack_kernel<<<(TOTAL/4)/256, 256, 0, stream>>>(pred, targ, pb, tb, listCnt);
    edge_dist_hist<<<EGRID, 1024, 0, stream>>>(pb, tb, bcnt, listCnt, list);
    percentile_kernel<<<1, 256, 0, stream>>>(pb, tb, bcnt, listCnt, list, out);
}

// Round 28
// 19.424 us; speedup vs baseline: 1.6439x; 1.6439x over previous
//
#include <hip/hip_runtime.h>
#include <stdint.h>

#define BB 2
#define DD 64
#define HH 128
#define WW 128
#define NVOX (DD*HH*WW)        // 2^20 per batch
#define TOTAL (BB*NVOX)        // 2097152
#define NWORDS (TOTAL/16)      // 131072 uint16 mask words per volume
#define EGRID (BB*DD*2)        // 256 blocks
#define BCNTN (EGRID*4)        // per-block private counter slots
#define CAP (1<<20)            // residual list capacity
#define MAXD2 36227            // 63^2+127^2+127^2
#define INF_I 0x7FFFFFFF

__device__ __forceinline__ int aload(const int* p)
{
    return __hip_atomic_load(p, __ATOMIC_RELAXED, __HIP_MEMORY_SCOPE_AGENT);
}

__device__ __forceinline__ void astore(int* p, int v)
{
    __hip_atomic_store(p, v, __ATOMIC_RELAXED, __HIP_MEMORY_SCOPE_AGENT);
}

// 4-bit spread: bit l -> bit 4l
__device__ __forceinline__ uint32_t spread4(uint32_t n)
{
    return (n & 1u) | ((n & 2u) << 3) | ((n & 4u) << 6) | ((n & 8u) << 9);
}

// ---------- bitpack: coalesced, deep-MLP (8 loads in flight) ---------------
// 512 blocks x 256 threads; each thread 4 float4 per volume at wave-coalesced
// offsets. All 8 independent loads issue before the first ballot waits.
__global__ __launch_bounds__(256)
void bitpack_kernel(const float* __restrict__ pred, const float* __restrict__ targ,
                    uint16_t* __restrict__ pb, uint16_t* __restrict__ tb,
                    int* __restrict__ listCnt)
{
    int tid = threadIdx.x;
    int lane = tid & 63, wv = tid >> 6;
    int base = blockIdx.x * 1024 + wv * 256;       // this wave's first float4 idx
    if (blockIdx.x == 0 && tid == 0) listCnt[0] = 0;

    const float4* p4 = (const float4*)pred;
    const float4* t4 = (const float4*)targ;
    float4 fp[4], ft[4];
    #pragma unroll
    for (int j = 0; j < 4; ++j) {
        fp[j] = p4[base + j * 64 + lane];
        ft[j] = t4[base + j * 64 + lane];
    }
    #pragma unroll
    for (int j = 0; j < 4; ++j) {
        int wbase = (base + j * 64) >> 2;          // first u16 word this round
        {
            float4 f = fp[j];
            uint64_t B0 = __ballot(f.x > 0.5f);
            uint64_t B1 = __ballot(f.y > 0.5f);
            uint64_t B2 = __ballot(f.z > 0.5f);
            uint64_t B3 = __ballot(f.w > 0.5f);
            if (lane < 16) {
                uint32_t n0 = (uint32_t)(B0 >> (4 * lane)) & 0xFu;
                uint32_t n1 = (uint32_t)(B1 >> (4 * lane)) & 0xFu;
                uint32_t n2 = (uint32_t)(B2 >> (4 * lane)) & 0xFu;
                uint32_t n3 = (uint32_t)(B3 >> (4 * lane)) & 0xFu;
                uint32_t word = spread4(n0) | (spread4(n1) << 1)
                              | (spread4(n2) << 2) | (spread4(n3) << 3);
                pb[wbase + lane] = (uint16_t)word;
            }
        }
        {
            float4 f = ft[j];
            uint64_t B0 = __ballot(f.x > 0.5f);
            uint64_t B1 = __ballot(f.y > 0.5f);
            uint64_t B2 = __ballot(f.z > 0.5f);
            uint64_t B3 = __ballot(f.w > 0.5f);
            if (lane < 16) {
                uint32_t n0 = (uint32_t)(B0 >> (4 * lane)) & 0xFu;
                uint32_t n1 = (uint32_t)(B1 >> (4 * lane)) & 0xFu;
                uint32_t n2 = (uint32_t)(B2 >> (4 * lane)) & 0xFu;
                uint32_t n3 = (uint32_t)(B3 >> (4 * lane)) & 0xFu;
                uint32_t word = spread4(n0) | (spread4(n1) << 1)
                              | (spread4(n2) << 2) | (spread4(n3) << 3);
                tb[wbase + lane] = (uint16_t)word;
            }
        }
    }
}

// ---------- bit-volume helpers (percentile kernel only) --------------------
__device__ __forceinline__ int getbit(const uint16_t* __restrict__ M,
                                      int b, int z, int y, int x)
{
    return (M[(((size_t)(b * DD + z)) << 10) + (y << 3) + (x >> 4)] >> (x & 15)) & 1;
}

__device__ __forceinline__ bool is_edge(const uint16_t* __restrict__ M,
                                        int b, int z, int y, int x)
{
    if (!getbit(M, b, z, y, x)) return false;
    if (x == 0 || x == WW-1 || y == 0 || y == HH-1 || z == 0 || z == DD-1) return true;
    int er = getbit(M,b,z,y,x-1) & getbit(M,b,z,y,x+1) &
             getbit(M,b,z,y-1,x) & getbit(M,b,z,y+1,x) &
             getbit(M,b,z-1,y,x) & getbit(M,b,z+1,y,x);
    return !er;
}

// ---------- LEAN edge + word-parallel r<=1 distance + private stores -------
__global__ __launch_bounds__(1024)
void edge_dist_hist(const uint16_t* __restrict__ pb, const uint16_t* __restrict__ tb,
                    int* __restrict__ bcnt, int* __restrict__ listCnt,
                    int* __restrict__ list)
{
    __shared__ uint16_t ownm[3][1024];   // own mask slices  z-1..z+1
    __shared__ uint16_t othm[5][1024];   // other mask slices z-2..z+2
    __shared__ uint16_t tedge[3][1024];  // other EDGE slices z-1..z+1
    __shared__ int lh[4];
    int gid = blockIdx.x, tid = threadIdx.x;
    int dir = gid & 1;
    int bz  = gid >> 1;
    int b   = bz >> 6, z = bz & (DD - 1);
    const uint16_t* own = dir ? tb : pb;   // dir0: E = pred edges
    const uint16_t* oth = dir ? pb : tb;   // dir0: distances to targ edges

    {   // cooperative load: 8 slices x 1024 words (zero out-of-range slices)
        int s = tid >> 7, off = (tid & 127) * 8;
        int zs = (s < 3) ? z + s - 1 : z + s - 5;
        const uint16_t* src = (s < 3) ? own : oth;
        uint16_t* dst = (s < 3) ? &ownm[s][off] : &othm[s - 3][off];
        if (zs >= 0 && zs < DD)
            *(uint4*)dst = *(const uint4*)(src + (((size_t)(b * DD + zs)) << 10) + off);
        else
            *(uint4*)dst = make_uint4(0, 0, 0, 0);
    }
    if (tid < 4) lh[tid] = 0;
    __syncthreads();

    int w = tid, y = w >> 3, wx = w & 7;

    // phase A: other-surface edge words for dz in {-1,0,1}
    #pragma unroll
    for (int dzi = 0; dzi < 3; ++dzi) {
        uint32_t c = othm[dzi + 1][w];
        uint32_t l = wx > 0 ? othm[dzi + 1][w - 1] : 0;
        uint32_t r = wx < 7 ? othm[dzi + 1][w + 1] : 0;
        uint32_t ext = (l >> 15) | (c << 1) | ((r & 1u) << 17);
        uint32_t m = (ext >> 1) & 0xFFFFu, L = ext & 0xFFFFu, R = (ext >> 2) & 0xFFFFu;
        uint32_t ym = y > 0   ? othm[dzi + 1][w - 8] : 0;
        uint32_t yp = y < 127 ? othm[dzi + 1][w + 8] : 0;
        uint32_t zm = othm[dzi][w], zp = othm[dzi + 2][w];
        uint32_t er = m & L & R & ym & yp & zm & zp;
        tedge[dzi][w] = (uint16_t)(m & ~er);
    }

    // E: own-surface edge word
    uint32_t E;
    {
        uint32_t c = ownm[1][w];
        uint32_t l = wx > 0 ? ownm[1][w - 1] : 0;
        uint32_t r = wx < 7 ? ownm[1][w + 1] : 0;
        uint32_t ext = (l >> 15) | (c << 1) | ((r & 1u) << 17);
        uint32_t m = (ext >> 1) & 0xFFFFu, L = ext & 0xFFFFu, R = (ext >> 2) & 0xFFFFu;
        uint32_t ym = y > 0   ? ownm[1][w - 8] : 0;
        uint32_t yp = y < 127 ? ownm[1][w + 8] : 0;
        uint32_t zm = ownm[0][w], zp = ownm[2][w];
        E = m & ~(m & L & R & ym & yp & zm & zp);
    }
    __syncthreads();   // tedge ready

    // phase B: M0..M3 (has oth-edge at d^2=0/1/2/3) from tedge ext rows
    uint32_t M0 = 0, M1 = 0, M2 = 0, M3 = 0;
    #pragma unroll
    for (int dzi = 0; dzi < 3; ++dzi) {
        #pragma unroll
        for (int dyy = -1; dyy <= 1; ++dyy) {
            int yy = y + dyy;
            uint32_t c = 0, l = 0, r = 0;
            if (yy >= 0 && yy < HH) {
                int w2 = (yy << 3) + wx;
                c = tedge[dzi][w2];
                l = wx > 0 ? tedge[dzi][w2 - 1] : 0;
                r = wx < 7 ? tedge[dzi][w2 + 1] : 0;
            }
            uint32_t ext = (l >> 15) | (c << 1) | ((r & 1u) << 17);
            uint32_t s0 = (ext >> 1) & 0xFFFFu;                      // dx = 0
            uint32_t s1 = (ext & 0xFFFFu) | ((ext >> 2) & 0xFFFFu);  // dx = +-1
            int a = (dzi == 1 ? 0 : 1) + (dyy == 0 ? 0 : 1);
            if (a == 0)      { M0 |= s0; M1 |= s1; }
            else if (a == 1) { M1 |= s0; M2 |= s1; }
            else             { M2 |= s0; M3 |= s1; }
        }
    }

    uint32_t rem = E;
    int c0 = __popc(rem & M0); rem &= ~M0;
    int c1 = __popc(rem & M1); rem &= ~M1;
    int c2 = __popc(rem & M2); rem &= ~M2;
    int c3 = __popc(rem & M3); rem &= ~M3;

    int g = b * 2 + dir;

    // residual voxels (boundary-clipped cubes, ~2-4 total): append POSITION
    while (rem) {
        int i = __builtin_ctz(rem); rem &= rem - 1;
        int x = wx * 16 + i;
        int pos = atomicAdd(listCnt, 1);
        if (pos < CAP)
            astore(&list[pos], g | (z << 2) | (y << 8) | (x << 15));
    }

    // wave reduce the 4 hot counters, one LDS atomic per wave, private store
    int lane = tid & 63;
    #pragma unroll
    for (int o = 1; o < 64; o <<= 1) {
        c0 += __shfl_xor(c0, o, 64);
        c1 += __shfl_xor(c1, o, 64);
        c2 += __shfl_xor(c2, o, 64);
        c3 += __shfl_xor(c3, o, 64);
    }
    if (lane == 0) {
        if (c0) atomicAdd(&lh[0], c0);
        if (c1) atomicAdd(&lh[1], c1);
        if (c2) atomicAdd(&lh[2], c2);
        if (c3) atomicAdd(&lh[3], c3);
    }
    __syncthreads();
    if (tid < 4)
        astore(&bcnt[gid * 4 + tid], lh[tid]);
}

// ---------- percentile tail: 1 block, wave w handles g=w -------------------
__global__ __launch_bounds__(256)
void percentile_kernel(const uint16_t* __restrict__ pb, const uint16_t* __restrict__ tb,
                       const int* __restrict__ bcnt, const int* __restrict__ listCnt,
                       int* __restrict__ list, float* __restrict__ out)
{
    int tid = threadIdx.x, lane = tid & 63, wv = tid >> 6;
    int nL = aload(listCnt); if (nL > CAP) nL = CAP;

    // resolve each residual with a WAVE-PARALLEL expanding-shell scan
    for (int idx = wv; idx < nL; idx += 4) {
        int e = aload(&list[idx]);
        int g2 = e & 3, zz0 = (e >> 2) & 63, yy0 = (e >> 8) & 127, xx0 = (e >> 15) & 127;
        const uint16_t* M = (g2 & 1) ? pb : tb;   // oth volume for this g
        int bb = g2 >> 1;
        int best = INF_I;
        for (int r = 2; r <= 127; ++r) {
            if (best <= r * r) break;
            int side = 2 * r + 1, npts = side * side * side;
            int lmin = INF_I;
            for (int k = lane; k < npts; k += 64) {
                int dzz = k / (side * side) - r;
                int r2  = k % (side * side);
                int dyy = r2 / side - r;
                int dxx = r2 % side - r;
                int cheb = max(abs(dzz), max(abs(dyy), abs(dxx)));
                if (cheb != r) continue;
                int zz = zz0 + dzz, yy = yy0 + dyy, xx = xx0 + dxx;
                if (zz < 0 || zz >= DD || yy < 0 || yy >= HH || xx < 0 || xx >= WW) continue;
                if (is_edge(M, bb, zz, yy, xx))
                    lmin = min(lmin, dzz*dzz + dyy*dyy + dxx*dxx);
            }
            #pragma unroll
            for (int o = 1; o < 64; o <<= 1) lmin = min(lmin, __shfl_xor(lmin, o, 64));
            best = min(best, lmin);
        }
        if (best > MAXD2) best = MAXD2;
        if (lane == 0)
            astore(&list[idx], (g2 << 16) | best);
    }
    __syncthreads();

    {
        int gg = wv;
        int bsel = gg >> 1, dsel = gg & 1;

        // sum this g's 64 per-block slots (one slot per lane)
        int gid2 = ((bsel * 64) + lane) * 2 + dsel;
        int h0 = aload(&bcnt[gid2 * 4 + 0]);
        int h1 = aload(&bcnt[gid2 * 4 + 1]);
        int h2 = aload(&bcnt[gid2 * 4 + 2]);
        int h3 = aload(&bcnt[gid2 * 4 + 3]);
        #pragma unroll
        for (int o = 1; o < 64; o <<= 1) {
            h0 += __shfl_xor(h0, o, 64);
            h1 += __shfl_xor(h1, o, 64);
            h2 += __shfl_xor(h2, o, 64);
            h3 += __shfl_xor(h3, o, 64);
        }

        // count of this g's list entries (wave-uniform after reduce)
        int cg = 0;
        for (int i = lane; i < nL; i += 64) {
            int e = aload(&list[i]);
            if ((e >> 16) == gg) cg++;
        }
        #pragma unroll
        for (int o = 1; o < 64; o <<= 1) cg += __shfl_xor(cg, o, 64);

        int n = h0 + h1 + h2 + h3 + cg;
        int hotTot = n - cg;

        float pos = 0.95f * (float)(n - 1);
        float fpos = floorf(pos);
        int lo = (int)fpos;
        int nm1 = n - 1; if (nm1 < 0) nm1 = 0;
        if (lo < 0) lo = 0;
        if (lo > nm1) lo = nm1;
        int hi = lo + 1; if (hi > nm1) hi = nm1;
        float frac = pos - fpos;

        int sel[2]; int ranks[2] = {lo, hi};
        #pragma unroll
        for (int ri = 0; ri < 2; ++ri) {
            int r = ranks[ri];
            int v;
            if      (r < h0)               v = 0;
            else if (r < h0 + h1)          v = 1;
            else if (r < h0 + h1 + h2)     v = 2;
            else if (r < hotTot)           v = 3;
            else {
                int k = r - hotTot;        // 0 <= k < cg
                int loV = 4, hiV = MAXD2;
                while (loV < hiV) {
                    int mid = (loV + hiV) >> 1;
                    int c = 0;
                    for (int i = lane; i < nL; i += 64) {
                        int e = aload(&list[i]);
                        if ((e >> 16) == gg && (e & 0xFFFF) <= mid) c++;
                    }
                    #pragma unroll
                    for (int o = 1; o < 64; o <<= 1) c += __shfl_xor(c, o, 64);
                    if (c >= k + 1) hiV = mid; else loV = mid + 1;
                }
                v = loV;
            }
            sel[ri] = v;
        }
        if (lane == 0) {
            float a = sqrtf((float)sel[0]);
            float bv = sqrtf((float)sel[1]);
            float val = a + frac * (bv - a);
            atomicMax((int*)out + (gg >> 1), __float_as_int(val));  // val>=0
        }
    }
}

extern "C" void kernel_launch(void* const* d_in, const int* in_sizes, int n_in,
                              void* d_out, int out_size, void* d_ws, size_t ws_size,
                              hipStream_t stream)
{
    const float* pred = (const float*)d_in[0];
    const float* targ = (const float*)d_in[1];
    float* out = (float*)d_out;

    uint8_t* ws = (uint8_t*)d_ws;
    uint16_t* pb = (uint16_t*)ws;                    // NWORDS u16 (16B-aligned)
    uint16_t* tb = pb + NWORDS;                      // NWORDS u16
    int* bcnt    = (int*)(tb + NWORDS);              // BCNTN ints (private slots)
    int* listCnt = bcnt + BCNTN;                     // 1 int (zeroed by bitpack)
    int* list    = listCnt + 1;                      // CAP ints (residuals)

    bitpack_kernel<<<512, 256, 0, stream>>>(pred, targ, pb, tb, listCnt);
    edge_dist_hist<<<EGRID, 1024, 0, stream>>>(pb, tb, bcnt, listCnt, list);
    percentile_kernel<<<1, 256, 0, stream>>>(pb, tb, bcnt, listCnt, list, out);
}